// Round 15
// baseline (165.129 us; speedup 1.0000x reference)
//
#include <hip/hip_runtime.h>

#define N_TOK 32768
#define D 256
#define DFF 1024
#define NE 8
#define TB 64    // tokens per expert_ffn block

typedef __attribute__((ext_vector_type(16))) float f32x16;
typedef __attribute__((ext_vector_type(8)))  short bf16x8;

// Raw barrier: LDS writes made visible (lgkmcnt(0)) but NO vmcnt drain --
// in-flight global weight loads survive the barrier (T3/T4; verified r8).
#define BARRIER() do {                                        \
    asm volatile("s_waitcnt lgkmcnt(0)" ::: "memory");        \
    __builtin_amdgcn_s_barrier();                             \
    __builtin_amdgcn_sched_barrier(0);                        \
} while (0)

// packed fp32x2 -> bf16x2 (RNE, single VALU inst)
__device__ __forceinline__ unsigned cvtpk(float lo, float hi) {
    unsigned r;
    asm("v_cvt_pk_bf16_f32 %0, %1, %2" : "=v"(r) : "v"(lo), "v"(hi));
    return r;
}

// ===========================================================================
// Fused gate + prep (1 launch). Blocks [0,128): GATE (fp64 logits, top-2,
// softmax, binning) with x->bf16 conversion fused. [128,1152): w1 prep;
// [1152,2176): w2 prep. Layout conventions verified rounds 2-14.
// ===========================================================================
__global__ __launch_bounds__(256) void prep_gate(
    const float* __restrict__ w1, const float* __restrict__ w2,
    short* __restrict__ w1f, short* __restrict__ w2f,
    const float* __restrict__ x, short* __restrict__ xb,
    const float* __restrict__ gw, const float* __restrict__ gb,
    int* __restrict__ cnt, int* __restrict__ bidx, float* __restrict__ bp,
    int2* __restrict__ opos) {
    const int b = blockIdx.x;
    if (b >= 128) {
        if (b < 1152) {
            const int gid  = (b - 128) * 256 + threadIdx.x;
            const int lane = gid & 63;
            const int frag = gid >> 6;
            const int dblk = frag & 15;
            const int fblk = (frag >> 4) & 31;
            const int e    = frag >> 9;
            const int l31 = lane & 31, g = lane >> 5;

            const float* src = w1 + ((size_t)e * 256 + dblk * 16 + g * 8) * 1024
                                  + fblk * 32 + l31;
            unsigned u[4];
#pragma unroll
            for (int jp = 0; jp < 4; ++jp)
                u[jp] = cvtpk(src[(size_t)(jp * 2) * 1024],
                              src[(size_t)(jp * 2 + 1) * 1024]);
            *(uint4*)(w1f + (size_t)gid * 8) = make_uint4(u[0], u[1], u[2], u[3]);
        } else {
            const int gid  = (b - 1152) * 256 + threadIdx.x;
            const int lane = gid & 63;
            const int frag = gid >> 6;
            const int fblk = frag & 63;
            const int cblk = (frag >> 6) & 7;
            const int e    = frag >> 9;
            const int l31 = lane & 31, g = lane >> 5;

            const float* src = w2 + ((size_t)e * 1024 + fblk * 16 + g * 8) * 256
                                  + cblk * 32 + l31;
            unsigned u[4];
#pragma unroll
            for (int jp = 0; jp < 4; ++jp)
                u[jp] = cvtpk(src[(size_t)(jp * 2) * 256],
                              src[(size_t)(jp * 2 + 1) * 256]);
            *(uint4*)(w2f + (size_t)gid * 8) = make_uint4(u[0], u[1], u[2], u[3]);
        }
        return;
    }

    // ---------------- gate (+ fused x->bf16) ----------------
    __shared__ float gws[2048];   // [d][e]
    __shared__ int   se1[256], se2[256];
    __shared__ float sp1[256], sp2[256];
    __shared__ int   hist[NE], base_[NE];

    const int tid = threadIdx.x;
#pragma unroll
    for (int i = 0; i < 8; ++i) gws[tid + 256 * i] = gw[tid + 256 * i];
    if (tid < NE) hist[tid] = 0;
    __syncthreads();

    const int t = b * 256 + tid;
    const float* xr = x + (size_t)t * D;
    short* xbr = xb + (size_t)t * D;

    double acc[NE];
#pragma unroll
    for (int e = 0; e < NE; ++e) acc[e] = 0.0;

    for (int d0 = 0; d0 < 256; d0 += 8) {
        float4 xv0 = *(const float4*)(xr + d0);
        float4 xv1 = *(const float4*)(xr + d0 + 4);
        float xa[8] = {xv0.x, xv0.y, xv0.z, xv0.w, xv1.x, xv1.y, xv1.z, xv1.w};
#pragma unroll
        for (int j = 0; j < 8; ++j) {
            float4 ga  = *(const float4*)&gws[(d0 + j) * 8];
            float4 gbb = *(const float4*)&gws[(d0 + j) * 8 + 4];
            double xd = (double)xa[j];
            acc[0] += xd * (double)ga.x;  acc[1] += xd * (double)ga.y;
            acc[2] += xd * (double)ga.z;  acc[3] += xd * (double)ga.w;
            acc[4] += xd * (double)gbb.x; acc[5] += xd * (double)gbb.y;
            acc[6] += xd * (double)gbb.z; acc[7] += xd * (double)gbb.w;
        }
        uint4 o;
        o.x = cvtpk(xv0.x, xv0.y);  o.y = cvtpk(xv0.z, xv0.w);
        o.z = cvtpk(xv1.x, xv1.y);  o.w = cvtpk(xv1.z, xv1.w);
        *(uint4*)(xbr + d0) = o;
    }

    double l[NE];
#pragma unroll
    for (int e = 0; e < NE; ++e) l[e] = acc[e] + (double)gb[e];
    int e1 = 0;
#pragma unroll
    for (int e = 1; e < NE; ++e) if (l[e] > l[e1]) e1 = e;
    int e2 = (e1 == 0) ? 1 : 0;
#pragma unroll
    for (int e = 0; e < NE; ++e) if (e != e1 && l[e] > l[e2]) e2 = e;

    double s = 0.0;
#pragma unroll
    for (int e = 0; e < NE; ++e) s += exp(l[e] - l[e1]);
    se1[tid] = e1; se2[tid] = e2;
    sp1[tid] = (float)(1.0 / s);
    sp2[tid] = (float)(exp(l[e2] - l[e1]) / s);
    __syncthreads();

    const int pos1 = atomicAdd(&hist[se1[tid]], 1);
    const int pos2 = atomicAdd(&hist[se2[tid]], 1);
    __syncthreads();
    if (tid < NE) base_[tid] = atomicAdd(&cnt[tid], hist[tid]);
    __syncthreads();

    const int o1 = se1[tid] * N_TOK + base_[se1[tid]] + pos1;
    const int o2 = se2[tid] * N_TOK + base_[se2[tid]] + pos2;
    bidx[o1] = t;  bp[o1] = sp1[tid];
    bidx[o2] = t;  bp[o2] = sp2[tid];
    opos[t] = make_int2(o1, o2);
}

// ===========================================================================
// Expert FFN v15 = v14 + CROSS-FC SOFTWARE PIPELINE: G1(fc+1) is fully
// independent of G2(fc) (G1 reads xs+w1; G2 reads hs[fc]+w2; the only
// hs-write, pack(fc+1), already sits behind a barrier) — so the two are
// merged into one 16-step loop with 4 MFMAs/step from two independent
// chains. The v14 wall (98us ~= SUM of pipe times) was phase serialization;
// the merged phase doubles independent MFMA work so L2/LDS latencies hide.
// Prologue G1(0) / epilogue G2(3) unmerged. 7 barriers (was 8).
// 512 thr / 8 waves, TB=64, fchunk=256, LDS 64.8KB, 2 blocks/CU.
// Layouts / pack / epilogue verbatim from verified rounds 2-14.
// ===========================================================================
__global__ __launch_bounds__(512, 4) void expert_ffn(
    const short* __restrict__ xb,
    const short* __restrict__ w1f,
    const short* __restrict__ w2f,
    const float* __restrict__ b1, const float* __restrict__ b2,
    const int* __restrict__ cnt, const int* __restrict__ bidx,
    const float* __restrict__ bp, float* __restrict__ out,
    float* __restrict__ yp, int staged) {
    const int e    = blockIdx.x & 7;
    const int tile = blockIdx.x >> 3;
    const int n_e  = cnt[e];
    const int row0 = tile * TB;
    if (row0 >= n_e) return;

    __shared__ short xs[16 * 64 * 16];   // 32KB [dblk][tok64][16] frag-major
    __shared__ short hs[32 * 512];       // 32KB [frag(kt*2+tp)][512]
    __shared__ int   tok_s[TB];
    __shared__ float p_s[TB];

    const int tid  = threadIdx.x;
    const int lane = tid & 63, wid = tid >> 6;   // wid 0..7
    const int l31  = lane & 31, g = lane >> 5;

    // compact yp base for this expert (deterministic prefix of cnt)
    int cbase = 0;
    for (int j = 0; j < e; ++j) cbase += cnt[j];

    if (tid < TB) {
        int r = row0 + tid;
        tok_s[tid] = (r < n_e) ? bidx[e * N_TOK + r] : -1;
        p_s[tid]   = (r < n_e) ? bp[e * N_TOK + r] : 0.f;
    }
    BARRIER();

    // ---- stage xb (bf16) -> xs frag-major: pure copies.
    {
        const int tok = tid >> 3;
        const int tk  = tok_s[tok];
        const short* xrow = xb + (size_t)(tk < 0 ? 0 : tk) * D;
#pragma unroll
        for (int i = 0; i < 2; ++i) {
            const int dblk = (tid & 7) * 2 + i;
            uint4 v0 = make_uint4(0, 0, 0, 0), v1 = make_uint4(0, 0, 0, 0);
            if (tk >= 0) {
                v0 = *(const uint4*)(xrow + dblk * 16);
                v1 = *(const uint4*)(xrow + dblk * 16 + 8);
            }
            short* dp = &xs[dblk * 1024 + tok * 16];
            *(uint4*)(dp)     = v0;
            *(uint4*)(dp + 8) = v1;
        }
    }

    f32x16 acc[2];   // [tp tok-half], cols wid*32 + l31
#pragma unroll
    for (int a = 0; a < 2; ++a)
#pragma unroll
        for (int r = 0; r < 16; ++r) acc[a][r] = 0.f;

    const short* w1e = w1f + (size_t)e * (32 * 16 * 512);
    const short* w2e = w2f + (size_t)e * (8 * 64 * 512);
    const float* b1e = b1 + e * DFF;

    BARRIER();   // xs ready

    // pack helper (mapping verbatim r5-r14)
#define PACK(FC, H0, H1)                                                      \
    do {                                                                      \
        _Pragma("unroll")                                                     \
        for (int tp = 0; tp < 2; ++tp) {                                      \
            const f32x16& hh = tp ? (H1) : (H0);                              \
            _Pragma("unroll")                                                 \
            for (int m = 0; m < 4; ++m) {                                     \
                float4 bq = *(const float4*)(b1e + (FC) * 256 + wid * 32 +    \
                                             8 * m + 4 * g);                  \
                float v0 = fmaxf(hh[4 * m + 0] + bq.x, 0.f);                  \
                float v1 = fmaxf(hh[4 * m + 1] + bq.y, 0.f);                  \
                float v2 = fmaxf(hh[4 * m + 2] + bq.z, 0.f);                  \
                float v3 = fmaxf(hh[4 * m + 3] + bq.w, 0.f);                  \
                uint2 pk;                                                     \
                pk.x = cvtpk(v0, v1);                                         \
                pk.y = cvtpk(v2, v3);                                         \
                const int fragid = (2 * wid + (m >> 1)) * 2 + tp;             \
                *(uint2*)&hs[fragid * 512 + ((m & 1) * 32 + l31) * 8 + 4 * g] \
                    = pk;                                                     \
            }                                                                 \
        }                                                                     \
    } while (0)

    // ---- prologue: G1(0) alone
    {
        f32x16 h0, h1;
#pragma unroll
        for (int r = 0; r < 16; ++r) { h0[r] = 0.f; h1[r] = 0.f; }
        const short* w1p = w1e + ((size_t)(0 * 8 + wid) * 16) * 512 + lane * 8;
        __builtin_amdgcn_s_setprio(1);
        {
            bf16x8 a0 = *(const bf16x8*)(w1p);
            bf16x8 x0 = *(const bf16x8*)&xs[l31 * 16 + g * 8];
            bf16x8 x1 = *(const bf16x8*)&xs[512 + l31 * 16 + g * 8];
#pragma unroll
            for (int db = 0; db < 16; ++db) {
                bf16x8 an, y0, y1;
                if (db < 15) {
                    an = *(const bf16x8*)(w1p + (db + 1) * 512);
                    y0 = *(const bf16x8*)&xs[(db + 1) * 1024 + l31 * 16 + g * 8];
                    y1 = *(const bf16x8*)&xs[(db + 1) * 1024 + 512 + l31 * 16 + g * 8];
                }
                h0 = __builtin_amdgcn_mfma_f32_32x32x16_bf16(a0, x0, h0, 0, 0, 0);
                h1 = __builtin_amdgcn_mfma_f32_32x32x16_bf16(a0, x1, h1, 0, 0, 0);
                if (db < 15) { a0 = an; x0 = y0; x1 = y1; }
            }
        }
        __builtin_amdgcn_s_setprio(0);
        PACK(0, h0, h1);
    }
    BARRIER();   // hs[0] ready

    for (int fc = 0; fc < 4; ++fc) {
        const short* w2p = w2e + ((size_t)wid * 64 + fc * 16) * 512 + lane * 8;
        if (fc < 3) {
            // ---------- MERGED: G2(fc) || G1(fc+1): two independent MFMA
            // chains, 4 MFMAs/step — L2/LDS latencies hide under each other.
            const short* w1p = w1e + ((size_t)((fc + 1) * 8 + wid) * 16) * 512 + lane * 8;
            f32x16 g0, g1;
#pragma unroll
            for (int r = 0; r < 16; ++r) { g0[r] = 0.f; g1[r] = 0.f; }

            __builtin_amdgcn_s_setprio(1);
            {
                bf16x8 wcur = *(const bf16x8*)(w2p);
                bf16x8 ha0  = *(const bf16x8*)&hs[0 * 512 + lane * 8];
                bf16x8 ha1  = *(const bf16x8*)&hs[1 * 512 + lane * 8];
                bf16x8 a0   = *(const bf16x8*)(w1p);
                bf16x8 x0   = *(const bf16x8*)&xs[l31 * 16 + g * 8];
                bf16x8 x1   = *(const bf16x8*)&xs[512 + l31 * 16 + g * 8];
#pragma unroll
                for (int s = 0; s < 16; ++s) {
                    bf16x8 wn, hb0, hb1, an, y0, y1;
                    if (s < 15) {
                        wn  = *(const bf16x8*)(w2p + (s + 1) * 512);
                        hb0 = *(const bf16x8*)&hs[((s + 1) * 2 + 0) * 512 + lane * 8];
                        hb1 = *(const bf16x8*)&hs[((s + 1) * 2 + 1) * 512 + lane * 8];
                        an  = *(const bf16x8*)(w1p + (s + 1) * 512);
                        y0  = *(const bf16x8*)&xs[(s + 1) * 1024 + l31 * 16 + g * 8];
                        y1  = *(const bf16x8*)&xs[(s + 1) * 1024 + 512 + l31 * 16 + g * 8];
                    }
                    acc[0] = __builtin_amdgcn_mfma_f32_32x32x16_bf16(ha0, wcur, acc[0], 0, 0, 0);
                    acc[1] = __builtin_amdgcn_mfma_f32_32x32x16_bf16(ha1, wcur, acc[1], 0, 0, 0);
                    g0 = __builtin_amdgcn_mfma_f32_32x32x16_bf16(a0, x0, g0, 0, 0, 0);
                    g1 = __builtin_amdgcn_mfma_f32_32x32x16_bf16(a0, x1, g1, 0, 0, 0);
                    if (s < 15) { wcur = wn; ha0 = hb0; ha1 = hb1; a0 = an; x0 = y0; x1 = y1; }
                }
            }
            __builtin_amdgcn_s_setprio(0);

            BARRIER();   // all waves done reading hs[fc]
            PACK(fc + 1, g0, g1);
            BARRIER();   // hs[fc+1] ready
        } else {
            // ---------- epilogue: G2(3) alone
            __builtin_amdgcn_s_setprio(1);
            {
                bf16x8 wcur = *(const bf16x8*)(w2p);
                bf16x8 ha0 = *(const bf16x8*)&hs[0 * 512 + lane * 8];
                bf16x8 ha1 = *(const bf16x8*)&hs[1 * 512 + lane * 8];
#pragma unroll
                for (int kt = 0; kt < 16; ++kt) {
                    bf16x8 wn, hb0, hb1;
                    if (kt < 15) {
                        wn  = *(const bf16x8*)(w2p + (kt + 1) * 512);
                        hb0 = *(const bf16x8*)&hs[((kt + 1) * 2 + 0) * 512 + lane * 8];
                        hb1 = *(const bf16x8*)&hs[((kt + 1) * 2 + 1) * 512 + lane * 8];
                    }
                    acc[0] = __builtin_amdgcn_mfma_f32_32x32x16_bf16(ha0, wcur, acc[0], 0, 0, 0);
                    acc[1] = __builtin_amdgcn_mfma_f32_32x32x16_bf16(ha1, wcur, acc[1], 0, 0, 0);
                    if (kt < 15) { wcur = wn; ha0 = hb0; ha1 = hb1; }
                }
            }
            __builtin_amdgcn_s_setprio(0);
        }
    }
#undef PACK

    // ---- epilogue ----
    const float* b2e = b2 + e * D;
    const int col = wid * 32 + l31;
    const float bv = b2e[col];
    if (staged) {
        float* ype = yp + ((size_t)(cbase + row0)) * 256;
#pragma unroll
        for (int tp = 0; tp < 2; ++tp) {
#pragma unroll
            for (int r = 0; r < 16; ++r) {
                const int tl = tp * 32 + (r & 3) + 8 * (r >> 2) + 4 * g;
                if (tok_s[tl] >= 0)
                    __builtin_nontemporal_store(
                        (acc[tp][r] + bv) * p_s[tl],
                        &ype[(size_t)tl * 256 + col]);
            }
        }
    } else {
#pragma unroll
        for (int tp = 0; tp < 2; ++tp) {
#pragma unroll
            for (int r = 0; r < 16; ++r) {
                const int tl = tp * 32 + (r & 3) + 8 * (r >> 2) + 4 * g;
                const int tk = tok_s[tl];
                if (tk >= 0)
                    atomicAdd(out + (size_t)tk * D + col,
                              (acc[tp][r] + bv) * p_s[tl]);
            }
        }
    }
}

// ===========================================================================
// Combine: out[t] = yp[compact(o1)] + yp[compact(o2)].
// ===========================================================================
__global__ __launch_bounds__(256) void combine(
    const float* __restrict__ yp, const int2* __restrict__ opos,
    const int* __restrict__ cnt, float* __restrict__ out) {
    __shared__ int cb[NE];
    if (threadIdx.x == 0) {
        int s = 0;
#pragma unroll
        for (int j = 0; j < NE; ++j) { cb[j] = s; s += cnt[j]; }
    }
    __syncthreads();
    const int gid   = blockIdx.x * 256 + threadIdx.x;  // float4 index
    const int t     = gid >> 6;
    const int lane4 = gid & 63;
    const int2 o = opos[t];
    const size_t r1 = (size_t)(cb[o.x >> 15] + (o.x & (N_TOK - 1)));
    const size_t r2 = (size_t)(cb[o.y >> 15] + (o.y & (N_TOK - 1)));
    const float4 a = ((const float4*)yp)[r1 * 64 + lane4];
    const float4 b = ((const float4*)yp)[r2 * 64 + lane4];
    float4 r;
    r.x = a.x + b.x; r.y = a.y + b.y; r.z = a.z + b.z; r.w = a.w + b.w;
    ((float4*)out)[gid] = r;
}

// ---------------------------------------------------------------------------
extern "C" void kernel_launch(void* const* d_in, const int* in_sizes, int n_in,
                              void* d_out, int out_size, void* d_ws, size_t ws_size,
                              hipStream_t stream) {
    const float* x  = (const float*)d_in[0];
    const float* gw = (const float*)d_in[1];
    const float* gb = (const float*)d_in[2];
    const float* w1 = (const float*)d_in[3];
    const float* b1 = (const float*)d_in[4];
    const float* w2 = (const float*)d_in[5];
    const float* b2 = (const float*)d_in[6];
    float* out = (float*)d_out;

    // ws (compact): cnt 256B | bidx 1MB | bp 1MB | opos 512KB
    //   | w1f 4MB | w2f 4MB | xb 16MB | yp 64MB  => 90.5MB total.
    char* ws = (char*)d_ws;
    size_t off = 0;
    int*   cnt   = (int*)(ws + off);  off += 256;
    int*   bidx  = (int*)(ws + off);  off += (size_t)NE * N_TOK * 4;
    float* bp    = (float*)(ws + off); off += (size_t)NE * N_TOK * 4;
    int2*  opos  = (int2*)(ws + off); off += (size_t)N_TOK * 8;
    short* w1f   = (short*)(ws + off); off += (size_t)NE * D * DFF * 2;
    short* w2f   = (short*)(ws + off); off += (size_t)NE * D * DFF * 2;
    short* xb    = (short*)(ws + off); off += (size_t)N_TOK * D * 2;
    float* yp    = (float*)(ws + off); off += (size_t)2 * N_TOK * D * 4;
    const int staged = (ws_size >= off) ? 1 : 0;

    hipMemsetAsync(cnt, 0, 256, stream);
    if (!staged)
        hipMemsetAsync(d_out, 0, (size_t)out_size * sizeof(float), stream);

    // fused: gate+x-conv (128, FIRST) + w1 prep (1024) + w2 prep (1024)
    prep_gate<<<128 + 2048, 256, 0, stream>>>(
        w1, w2, w1f, w2f, x, xb, gw, gb, cnt, bidx, bp, opos);
    expert_ffn<<<NE * (N_TOK / TB), 512, 0, stream>>>(xb, w1f, w2f, b1, b2,
                                                      cnt, bidx, bp, out, yp, staged);
    if (staged)
        combine<<<(N_TOK * D / 4) / 256, 256, 0, stream>>>(yp, opos, cnt, out);
}

// Round 16
// 145.546 us; speedup vs baseline: 1.1346x; 1.1346x over previous
//
#include <hip/hip_runtime.h>

#define N_TOK 32768
#define D 256
#define DFF 1024
#define NE 8
#define TB 64    // tokens per expert_ffn block

typedef __attribute__((ext_vector_type(16))) float f32x16;
typedef __attribute__((ext_vector_type(8)))  short bf16x8;

// Raw barrier: LDS writes made visible (lgkmcnt(0)) but NO vmcnt drain --
// in-flight global weight loads survive the barrier (T3/T4; verified r8).
#define BARRIER() do {                                        \
    asm volatile("s_waitcnt lgkmcnt(0)" ::: "memory");        \
    __builtin_amdgcn_s_barrier();                             \
    __builtin_amdgcn_sched_barrier(0);                        \
} while (0)

// packed fp32x2 -> bf16x2 (RNE, single VALU inst)
__device__ __forceinline__ unsigned cvtpk(float lo, float hi) {
    unsigned r;
    asm("v_cvt_pk_bf16_f32 %0, %1, %2" : "=v"(r) : "v"(lo), "v"(hi));
    return r;
}

// ===========================================================================
// Fused gate + prep (1 launch). Blocks [0,128): GATE (fp64 logits, top-2,
// softmax, binning) with x->bf16 conversion fused (x row already read for
// logits). [128,1152): w1 prep; [1152,2176): w2 prep. Gate first: longest-
// pole fp64 work starts at t=0.
//  w1f: frag=(e*32+fblk)*16+dblk; elem f=fblk*32+(l&31), d=dblk*16+(l>>5)*8+j
//  w2f: frag=(e*8+cblk)*64+fblk; elem col=cblk*32+(l&31), f=fblk*16+(l>>5)*8+j
//  (layout conventions verified rounds 2-15)
// ===========================================================================
__global__ __launch_bounds__(256) void prep_gate(
    const float* __restrict__ w1, const float* __restrict__ w2,
    short* __restrict__ w1f, short* __restrict__ w2f,
    const float* __restrict__ x, short* __restrict__ xb,
    const float* __restrict__ gw, const float* __restrict__ gb,
    int* __restrict__ cnt, int* __restrict__ bidx, float* __restrict__ bp,
    int2* __restrict__ opos) {
    const int b = blockIdx.x;
    if (b >= 128) {
        if (b < 1152) {
            const int gid  = (b - 128) * 256 + threadIdx.x;
            const int lane = gid & 63;
            const int frag = gid >> 6;
            const int dblk = frag & 15;
            const int fblk = (frag >> 4) & 31;
            const int e    = frag >> 9;
            const int l31 = lane & 31, g = lane >> 5;

            const float* src = w1 + ((size_t)e * 256 + dblk * 16 + g * 8) * 1024
                                  + fblk * 32 + l31;
            unsigned u[4];
#pragma unroll
            for (int jp = 0; jp < 4; ++jp)
                u[jp] = cvtpk(src[(size_t)(jp * 2) * 1024],
                              src[(size_t)(jp * 2 + 1) * 1024]);
            *(uint4*)(w1f + (size_t)gid * 8) = make_uint4(u[0], u[1], u[2], u[3]);
        } else {
            const int gid  = (b - 1152) * 256 + threadIdx.x;
            const int lane = gid & 63;
            const int frag = gid >> 6;
            const int fblk = frag & 63;
            const int cblk = (frag >> 6) & 7;
            const int e    = frag >> 9;
            const int l31 = lane & 31, g = lane >> 5;

            const float* src = w2 + ((size_t)e * 1024 + fblk * 16 + g * 8) * 256
                                  + cblk * 32 + l31;
            unsigned u[4];
#pragma unroll
            for (int jp = 0; jp < 4; ++jp)
                u[jp] = cvtpk(src[(size_t)(jp * 2) * 256],
                              src[(size_t)(jp * 2 + 1) * 256]);
            *(uint4*)(w2f + (size_t)gid * 8) = make_uint4(u[0], u[1], u[2], u[3]);
        }
        return;
    }

    // ---------------- gate (+ fused x->bf16) ----------------
    __shared__ float gws[2048];   // [d][e]
    __shared__ int   se1[256], se2[256];
    __shared__ float sp1[256], sp2[256];
    __shared__ int   hist[NE], base_[NE];

    const int tid = threadIdx.x;
#pragma unroll
    for (int i = 0; i < 8; ++i) gws[tid + 256 * i] = gw[tid + 256 * i];
    if (tid < NE) hist[tid] = 0;
    __syncthreads();

    const int t = b * 256 + tid;
    const float* xr = x + (size_t)t * D;
    short* xbr = xb + (size_t)t * D;

    double acc[NE];
#pragma unroll
    for (int e = 0; e < NE; ++e) acc[e] = 0.0;

    for (int d0 = 0; d0 < 256; d0 += 8) {
        float4 xv0 = *(const float4*)(xr + d0);
        float4 xv1 = *(const float4*)(xr + d0 + 4);
        float xa[8] = {xv0.x, xv0.y, xv0.z, xv0.w, xv1.x, xv1.y, xv1.z, xv1.w};
#pragma unroll
        for (int j = 0; j < 8; ++j) {
            float4 ga  = *(const float4*)&gws[(d0 + j) * 8];
            float4 gbb = *(const float4*)&gws[(d0 + j) * 8 + 4];
            double xd = (double)xa[j];
            acc[0] += xd * (double)ga.x;  acc[1] += xd * (double)ga.y;
            acc[2] += xd * (double)ga.z;  acc[3] += xd * (double)ga.w;
            acc[4] += xd * (double)gbb.x; acc[5] += xd * (double)gbb.y;
            acc[6] += xd * (double)gbb.z; acc[7] += xd * (double)gbb.w;
        }
        uint4 o;
        o.x = cvtpk(xv0.x, xv0.y);  o.y = cvtpk(xv0.z, xv0.w);
        o.z = cvtpk(xv1.x, xv1.y);  o.w = cvtpk(xv1.z, xv1.w);
        *(uint4*)(xbr + d0) = o;
    }

    double l[NE];
#pragma unroll
    for (int e = 0; e < NE; ++e) l[e] = acc[e] + (double)gb[e];
    int e1 = 0;
#pragma unroll
    for (int e = 1; e < NE; ++e) if (l[e] > l[e1]) e1 = e;
    int e2 = (e1 == 0) ? 1 : 0;
#pragma unroll
    for (int e = 0; e < NE; ++e) if (e != e1 && l[e] > l[e2]) e2 = e;

    double s = 0.0;
#pragma unroll
    for (int e = 0; e < NE; ++e) s += exp(l[e] - l[e1]);
    se1[tid] = e1; se2[tid] = e2;
    sp1[tid] = (float)(1.0 / s);
    sp2[tid] = (float)(exp(l[e2] - l[e1]) / s);
    __syncthreads();

    const int pos1 = atomicAdd(&hist[se1[tid]], 1);
    const int pos2 = atomicAdd(&hist[se2[tid]], 1);
    __syncthreads();
    if (tid < NE) base_[tid] = atomicAdd(&cnt[tid], hist[tid]);
    __syncthreads();

    const int o1 = se1[tid] * N_TOK + base_[se1[tid]] + pos1;
    const int o2 = se2[tid] * N_TOK + base_[se2[tid]] + pos2;
    bidx[o1] = t;  bp[o1] = sp1[tid];
    bidx[o2] = t;  bp[o2] = sp2[tid];
    opos[t] = make_int2(o1, o2);
}

// ===========================================================================
// Expert FFN v16 == v14 exactly (REVERT of v15's merged pipeline, which
// regressed 98->126us: merged loop put 6 ds_read_b128/step on the LDS pipe
// (~72cyc issue vs 32cyc MFMA) and doubled live-range pressure). v14 config
// {1-deep rolling loads, 8 raw barriers (no vmcnt drain), setprio, cvt_pk
// pack, bf16 x staging, compact yp} is the measured optimum: 98us,
// MfmaUtil 30.7%, 2 blocks/CU x 8 waves.
// ===========================================================================
__global__ __launch_bounds__(512, 4) void expert_ffn(
    const short* __restrict__ xb,
    const short* __restrict__ w1f,
    const short* __restrict__ w2f,
    const float* __restrict__ b1, const float* __restrict__ b2,
    const int* __restrict__ cnt, const int* __restrict__ bidx,
    const float* __restrict__ bp, float* __restrict__ out,
    float* __restrict__ yp, int staged) {
    const int e    = blockIdx.x & 7;
    const int tile = blockIdx.x >> 3;
    const int n_e  = cnt[e];
    const int row0 = tile * TB;
    if (row0 >= n_e) return;

    __shared__ short xs[16 * 64 * 16];   // 32KB [dblk][tok64][16] frag-major
    __shared__ short hs[32 * 512];       // 32KB [frag(kt*2+tp)][512]
    __shared__ int   tok_s[TB];
    __shared__ float p_s[TB];

    const int tid  = threadIdx.x;
    const int lane = tid & 63, wid = tid >> 6;   // wid 0..7
    const int l31  = lane & 31, g = lane >> 5;

    // compact yp base for this expert: sum of cnt[j], j<e (deterministic)
    int cbase = 0;
    for (int j = 0; j < e; ++j) cbase += cnt[j];

    if (tid < TB) {
        int r = row0 + tid;
        tok_s[tid] = (r < n_e) ? bidx[e * N_TOK + r] : -1;
        p_s[tid]   = (r < n_e) ? bp[e * N_TOK + r] : 0.f;
    }
    BARRIER();

    // ---- stage xb (bf16) -> xs frag-major: pure copies, no VALU.
    {
        const int tok = tid >> 3;
        const int tk  = tok_s[tok];
        const short* xrow = xb + (size_t)(tk < 0 ? 0 : tk) * D;
#pragma unroll
        for (int i = 0; i < 2; ++i) {
            const int dblk = (tid & 7) * 2 + i;
            uint4 v0 = make_uint4(0, 0, 0, 0), v1 = make_uint4(0, 0, 0, 0);
            if (tk >= 0) {
                v0 = *(const uint4*)(xrow + dblk * 16);
                v1 = *(const uint4*)(xrow + dblk * 16 + 8);
            }
            short* dp = &xs[dblk * 1024 + tok * 16];
            *(uint4*)(dp)     = v0;
            *(uint4*)(dp + 8) = v1;
        }
    }

    f32x16 acc[2];   // [tp tok-half], cols wid*32 + l31
#pragma unroll
    for (int a = 0; a < 2; ++a)
#pragma unroll
        for (int r = 0; r < 16; ++r) acc[a][r] = 0.f;

    const short* w1e = w1f + (size_t)e * (32 * 16 * 512);
    const short* w2e = w2f + (size_t)e * (8 * 64 * 512);
    const float* b1e = b1 + e * DFF;

    BARRIER();   // xs ready

    for (int fc = 0; fc < 4; ++fc) {
        // ---------- GEMM1: wave wid -> f-strip [fc*256+wid*32, +32) x 64 tok
        f32x16 h0, h1;
#pragma unroll
        for (int r = 0; r < 16; ++r) { h0[r] = 0.f; h1[r] = 0.f; }

        const short* w1p = w1e + ((size_t)(fc * 8 + wid) * 16) * 512 + lane * 8;
        __builtin_amdgcn_s_setprio(1);
        {
            bf16x8 a0 = *(const bf16x8*)(w1p);
            bf16x8 x0 = *(const bf16x8*)&xs[l31 * 16 + g * 8];
            bf16x8 x1 = *(const bf16x8*)&xs[512 + l31 * 16 + g * 8];
#pragma unroll
            for (int db = 0; db < 16; ++db) {
                bf16x8 an, y0, y1;
                if (db < 15) {
                    an = *(const bf16x8*)(w1p + (db + 1) * 512);
                    y0 = *(const bf16x8*)&xs[(db + 1) * 1024 + l31 * 16 + g * 8];
                    y1 = *(const bf16x8*)&xs[(db + 1) * 1024 + 512 + l31 * 16 + g * 8];
                }
                h0 = __builtin_amdgcn_mfma_f32_32x32x16_bf16(a0, x0, h0, 0, 0, 0);
                h1 = __builtin_amdgcn_mfma_f32_32x32x16_bf16(a0, x1, h1, 0, 0, 0);
                if (db < 15) { a0 = an; x0 = y0; x1 = y1; }
            }
        }
        __builtin_amdgcn_s_setprio(0);

        BARRIER();   // prev GEMM2 hs reads done

        // ---------- pack: bias+relu + cvt_pk -> hs frag-major
#pragma unroll
        for (int tp = 0; tp < 2; ++tp) {
            const f32x16& hh = tp ? h1 : h0;
#pragma unroll
            for (int m = 0; m < 4; ++m) {
                float4 bq = *(const float4*)(b1e + fc * 256 + wid * 32 + 8 * m + 4 * g);
                float v0 = fmaxf(hh[4 * m + 0] + bq.x, 0.f);
                float v1 = fmaxf(hh[4 * m + 1] + bq.y, 0.f);
                float v2 = fmaxf(hh[4 * m + 2] + bq.z, 0.f);
                float v3 = fmaxf(hh[4 * m + 3] + bq.w, 0.f);
                uint2 pk;
                pk.x = cvtpk(v0, v1);
                pk.y = cvtpk(v2, v3);
                const int fragid = (2 * wid + (m >> 1)) * 2 + tp;
                *(uint2*)&hs[fragid * 512 + ((m & 1) * 32 + l31) * 8 + 4 * g] = pk;
            }
        }

        // ---------- prefetch first w2 frag above the barrier
        const short* w2p = w2e + ((size_t)wid * 64 + fc * 16) * 512 + lane * 8;
        bf16x8 wcur = *(const bf16x8*)(w2p);

        BARRIER();   // hs ready; in-flight vmem NOT drained

        // ---------- GEMM2: wave wid -> cols [wid*32, +32), k over 256 f
        __builtin_amdgcn_s_setprio(1);
        {
            bf16x8 ha0 = *(const bf16x8*)&hs[0 * 512 + lane * 8];
            bf16x8 ha1 = *(const bf16x8*)&hs[1 * 512 + lane * 8];
#pragma unroll
            for (int kt = 0; kt < 16; ++kt) {
                bf16x8 wn, hb0, hb1;
                if (kt < 15) {
                    wn  = *(const bf16x8*)(w2p + (kt + 1) * 512);
                    hb0 = *(const bf16x8*)&hs[((kt + 1) * 2 + 0) * 512 + lane * 8];
                    hb1 = *(const bf16x8*)&hs[((kt + 1) * 2 + 1) * 512 + lane * 8];
                }
                acc[0] = __builtin_amdgcn_mfma_f32_32x32x16_bf16(ha0, wcur, acc[0], 0, 0, 0);
                acc[1] = __builtin_amdgcn_mfma_f32_32x32x16_bf16(ha1, wcur, acc[1], 0, 0, 0);
                if (kt < 15) { wcur = wn; ha0 = hb0; ha1 = hb1; }
            }
        }
        __builtin_amdgcn_s_setprio(0);
    }

    // ---- epilogue ----
    const float* b2e = b2 + e * D;
    const int col = wid * 32 + l31;
    const float bv = b2e[col];
    if (staged) {
        // compact rows: [cbase + row0, cbase + row0 + TB)
        float* ype = yp + ((size_t)(cbase + row0)) * 256;
#pragma unroll
        for (int tp = 0; tp < 2; ++tp) {
#pragma unroll
            for (int r = 0; r < 16; ++r) {
                const int tl = tp * 32 + (r & 3) + 8 * (r >> 2) + 4 * g;
                if (tok_s[tl] >= 0)
                    __builtin_nontemporal_store(
                        (acc[tp][r] + bv) * p_s[tl],
                        &ype[(size_t)tl * 256 + col]);
            }
        }
    } else {
#pragma unroll
        for (int tp = 0; tp < 2; ++tp) {
#pragma unroll
            for (int r = 0; r < 16; ++r) {
                const int tl = tp * 32 + (r & 3) + 8 * (r >> 2) + 4 * g;
                const int tk = tok_s[tl];
                if (tk >= 0)
                    atomicAdd(out + (size_t)tk * D + col,
                              (acc[tp][r] + bv) * p_s[tl]);
            }
        }
    }
}

// ===========================================================================
// Combine: out[t] = yp[compact(o1)] + yp[compact(o2)], compact(o) =
// prefix(cnt)[o>>15] + (o & 32767). One wave per token row.
// ===========================================================================
__global__ __launch_bounds__(256) void combine(
    const float* __restrict__ yp, const int2* __restrict__ opos,
    const int* __restrict__ cnt, float* __restrict__ out) {
    __shared__ int cb[NE];
    if (threadIdx.x == 0) {
        int s = 0;
#pragma unroll
        for (int j = 0; j < NE; ++j) { cb[j] = s; s += cnt[j]; }
    }
    __syncthreads();
    const int gid   = blockIdx.x * 256 + threadIdx.x;  // float4 index
    const int t     = gid >> 6;
    const int lane4 = gid & 63;
    const int2 o = opos[t];
    const size_t r1 = (size_t)(cb[o.x >> 15] + (o.x & (N_TOK - 1)));
    const size_t r2 = (size_t)(cb[o.y >> 15] + (o.y & (N_TOK - 1)));
    const float4 a = ((const float4*)yp)[r1 * 64 + lane4];
    const float4 b = ((const float4*)yp)[r2 * 64 + lane4];
    float4 r;
    r.x = a.x + b.x; r.y = a.y + b.y; r.z = a.z + b.z; r.w = a.w + b.w;
    ((float4*)out)[gid] = r;
}

// ---------------------------------------------------------------------------
extern "C" void kernel_launch(void* const* d_in, const int* in_sizes, int n_in,
                              void* d_out, int out_size, void* d_ws, size_t ws_size,
                              hipStream_t stream) {
    const float* x  = (const float*)d_in[0];
    const float* gw = (const float*)d_in[1];
    const float* gb = (const float*)d_in[2];
    const float* w1 = (const float*)d_in[3];
    const float* b1 = (const float*)d_in[4];
    const float* w2 = (const float*)d_in[5];
    const float* b2 = (const float*)d_in[6];
    float* out = (float*)d_out;

    // ws (compact): cnt 256B | bidx 1MB | bp 1MB | opos 512KB
    //   | w1f 4MB | w2f 4MB | xb 16MB | yp 64MB  => 90.5MB total.
    char* ws = (char*)d_ws;
    size_t off = 0;
    int*   cnt   = (int*)(ws + off);  off += 256;
    int*   bidx  = (int*)(ws + off);  off += (size_t)NE * N_TOK * 4;
    float* bp    = (float*)(ws + off); off += (size_t)NE * N_TOK * 4;
    int2*  opos  = (int2*)(ws + off); off += (size_t)N_TOK * 8;
    short* w1f   = (short*)(ws + off); off += (size_t)NE * D * DFF * 2;
    short* w2f   = (short*)(ws + off); off += (size_t)NE * D * DFF * 2;
    short* xb    = (short*)(ws + off); off += (size_t)N_TOK * D * 2;
    float* yp    = (float*)(ws + off); off += (size_t)2 * N_TOK * D * 4;
    const int staged = (ws_size >= off) ? 1 : 0;

    hipMemsetAsync(cnt, 0, 256, stream);
    if (!staged)
        hipMemsetAsync(d_out, 0, (size_t)out_size * sizeof(float), stream);

    // fused: gate+x-conv (128, FIRST) + w1 prep (1024) + w2 prep (1024)
    prep_gate<<<128 + 2048, 256, 0, stream>>>(
        w1, w2, w1f, w2f, x, xb, gw, gb, cnt, bidx, bp, opos);
    expert_ffn<<<NE * (N_TOK / TB), 512, 0, stream>>>(xb, w1f, w2f, b1, b2,
                                                      cnt, bidx, bp, out, yp, staged);
    if (staged)
        combine<<<(N_TOK * D / 4) / 256, 256, 0, stream>>>(yp, opos, cnt, out);
}

// Round 17
// 141.852 us; speedup vs baseline: 1.1641x; 1.0260x over previous
//
#include <hip/hip_runtime.h>

#define N_TOK 32768
#define D 256
#define DFF 1024
#define NE 8
#define TB 64    // tokens per expert_ffn block

typedef __attribute__((ext_vector_type(16))) float f32x16;
typedef __attribute__((ext_vector_type(8)))  short bf16x8;

// Raw barrier: LDS writes made visible (lgkmcnt(0)) but NO vmcnt drain --
// in-flight global weight loads survive the barrier (T3/T4; verified r8).
#define BARRIER() do {                                        \
    asm volatile("s_waitcnt lgkmcnt(0)" ::: "memory");        \
    __builtin_amdgcn_s_barrier();                             \
    __builtin_amdgcn_sched_barrier(0);                        \
} while (0)

// packed fp32x2 -> bf16x2 (RNE, single VALU inst)
__device__ __forceinline__ unsigned cvtpk(float lo, float hi) {
    unsigned r;
    asm("v_cvt_pk_bf16_f32 %0, %1, %2" : "=v"(r) : "v"(lo), "v"(hi));
    return r;
}

// scalar fp32 -> bf16 (RNE) for the scattered epilogue stores
__device__ __forceinline__ unsigned short f2bf(float f) {
    union { float f; unsigned u; } v; v.f = f;
    unsigned r = v.u + 0x7FFFu + ((v.u >> 16) & 1u);
    return (unsigned short)(r >> 16);
}

__device__ __forceinline__ float bf2f(unsigned short u) {
    union { unsigned u; float f; } v; v.u = (unsigned)u << 16;
    return v.f;
}

// ===========================================================================
// Fused gate + prep (1 launch). Blocks [0,128): GATE (fp64 logits, top-2,
// softmax, binning) with x->bf16 conversion fused. [128,1152): w1 prep;
// [1152,2176): w2 prep. Layout conventions verified rounds 2-16.
//  w1f: frag=(e*32+fblk)*16+dblk; elem f=fblk*32+(l&31), d=dblk*16+(l>>5)*8+j
//  w2f: frag=(e*8+cblk)*64+fblk; elem col=cblk*32+(l&31), f=fblk*16+(l>>5)*8+j
// ===========================================================================
__global__ __launch_bounds__(256) void prep_gate(
    const float* __restrict__ w1, const float* __restrict__ w2,
    short* __restrict__ w1f, short* __restrict__ w2f,
    const float* __restrict__ x, short* __restrict__ xb,
    const float* __restrict__ gw, const float* __restrict__ gb,
    int* __restrict__ cnt, int* __restrict__ bidx, float* __restrict__ bp,
    int2* __restrict__ opos) {
    const int b = blockIdx.x;
    if (b >= 128) {
        if (b < 1152) {
            const int gid  = (b - 128) * 256 + threadIdx.x;
            const int lane = gid & 63;
            const int frag = gid >> 6;
            const int dblk = frag & 15;
            const int fblk = (frag >> 4) & 31;
            const int e    = frag >> 9;
            const int l31 = lane & 31, g = lane >> 5;

            const float* src = w1 + ((size_t)e * 256 + dblk * 16 + g * 8) * 1024
                                  + fblk * 32 + l31;
            unsigned u[4];
#pragma unroll
            for (int jp = 0; jp < 4; ++jp)
                u[jp] = cvtpk(src[(size_t)(jp * 2) * 1024],
                              src[(size_t)(jp * 2 + 1) * 1024]);
            *(uint4*)(w1f + (size_t)gid * 8) = make_uint4(u[0], u[1], u[2], u[3]);
        } else {
            const int gid  = (b - 1152) * 256 + threadIdx.x;
            const int lane = gid & 63;
            const int frag = gid >> 6;
            const int fblk = frag & 63;
            const int cblk = (frag >> 6) & 7;
            const int e    = frag >> 9;
            const int l31 = lane & 31, g = lane >> 5;

            const float* src = w2 + ((size_t)e * 1024 + fblk * 16 + g * 8) * 256
                                  + cblk * 32 + l31;
            unsigned u[4];
#pragma unroll
            for (int jp = 0; jp < 4; ++jp)
                u[jp] = cvtpk(src[(size_t)(jp * 2) * 256],
                              src[(size_t)(jp * 2 + 1) * 256]);
            *(uint4*)(w2f + (size_t)gid * 8) = make_uint4(u[0], u[1], u[2], u[3]);
        }
        return;
    }

    // ---------------- gate (+ fused x->bf16) ----------------
    __shared__ float gws[2048];   // [d][e]
    __shared__ int   se1[256], se2[256];
    __shared__ float sp1[256], sp2[256];
    __shared__ int   hist[NE], base_[NE];

    const int tid = threadIdx.x;
#pragma unroll
    for (int i = 0; i < 8; ++i) gws[tid + 256 * i] = gw[tid + 256 * i];
    if (tid < NE) hist[tid] = 0;
    __syncthreads();

    const int t = b * 256 + tid;
    const float* xr = x + (size_t)t * D;
    short* xbr = xb + (size_t)t * D;

    double acc[NE];
#pragma unroll
    for (int e = 0; e < NE; ++e) acc[e] = 0.0;

    for (int d0 = 0; d0 < 256; d0 += 8) {
        float4 xv0 = *(const float4*)(xr + d0);
        float4 xv1 = *(const float4*)(xr + d0 + 4);
        float xa[8] = {xv0.x, xv0.y, xv0.z, xv0.w, xv1.x, xv1.y, xv1.z, xv1.w};
#pragma unroll
        for (int j = 0; j < 8; ++j) {
            float4 ga  = *(const float4*)&gws[(d0 + j) * 8];
            float4 gbb = *(const float4*)&gws[(d0 + j) * 8 + 4];
            double xd = (double)xa[j];
            acc[0] += xd * (double)ga.x;  acc[1] += xd * (double)ga.y;
            acc[2] += xd * (double)ga.z;  acc[3] += xd * (double)ga.w;
            acc[4] += xd * (double)gbb.x; acc[5] += xd * (double)gbb.y;
            acc[6] += xd * (double)gbb.z; acc[7] += xd * (double)gbb.w;
        }
        uint4 o;
        o.x = cvtpk(xv0.x, xv0.y);  o.y = cvtpk(xv0.z, xv0.w);
        o.z = cvtpk(xv1.x, xv1.y);  o.w = cvtpk(xv1.z, xv1.w);
        *(uint4*)(xbr + d0) = o;
    }

    double l[NE];
#pragma unroll
    for (int e = 0; e < NE; ++e) l[e] = acc[e] + (double)gb[e];
    int e1 = 0;
#pragma unroll
    for (int e = 1; e < NE; ++e) if (l[e] > l[e1]) e1 = e;
    int e2 = (e1 == 0) ? 1 : 0;
#pragma unroll
    for (int e = 0; e < NE; ++e) if (e != e1 && l[e] > l[e2]) e2 = e;

    double s = 0.0;
#pragma unroll
    for (int e = 0; e < NE; ++e) s += exp(l[e] - l[e1]);
    se1[tid] = e1; se2[tid] = e2;
    sp1[tid] = (float)(1.0 / s);
    sp2[tid] = (float)(exp(l[e2] - l[e1]) / s);
    __syncthreads();

    const int pos1 = atomicAdd(&hist[se1[tid]], 1);
    const int pos2 = atomicAdd(&hist[se2[tid]], 1);
    __syncthreads();
    if (tid < NE) base_[tid] = atomicAdd(&cnt[tid], hist[tid]);
    __syncthreads();

    const int o1 = se1[tid] * N_TOK + base_[se1[tid]] + pos1;
    const int o2 = se2[tid] * N_TOK + base_[se2[tid]] + pos2;
    bidx[o1] = t;  bp[o1] = sp1[tid];
    bidx[o2] = t;  bp[o2] = sp2[tid];
    opos[t] = make_int2(o1, o2);
}

// ===========================================================================
// Expert FFN v17 = v14/v16 (measured optimum: 98us, MfmaUtil 30.7%) with
// the staged epilogue storing partials as BF16 (halves epilogue write bytes
// and combine's read bytes; accuracy audit: +<=2e-3 worst-case vs 5.23e-3
// threshold). tok_s>=0 guard retained — unguarded pad-row writes would
// corrupt the next expert's compact rows.
// ===========================================================================
__global__ __launch_bounds__(512, 4) void expert_ffn(
    const short* __restrict__ xb,
    const short* __restrict__ w1f,
    const short* __restrict__ w2f,
    const float* __restrict__ b1, const float* __restrict__ b2,
    const int* __restrict__ cnt, const int* __restrict__ bidx,
    const float* __restrict__ bp, float* __restrict__ out,
    unsigned short* __restrict__ yp, int staged) {
    const int e    = blockIdx.x & 7;
    const int tile = blockIdx.x >> 3;
    const int n_e  = cnt[e];
    const int row0 = tile * TB;
    if (row0 >= n_e) return;

    __shared__ short xs[16 * 64 * 16];   // 32KB [dblk][tok64][16] frag-major
    __shared__ short hs[32 * 512];       // 32KB [frag(kt*2+tp)][512]
    __shared__ int   tok_s[TB];
    __shared__ float p_s[TB];

    const int tid  = threadIdx.x;
    const int lane = tid & 63, wid = tid >> 6;   // wid 0..7
    const int l31  = lane & 31, g = lane >> 5;

    // compact yp base for this expert: sum of cnt[j], j<e (deterministic)
    int cbase = 0;
    for (int j = 0; j < e; ++j) cbase += cnt[j];

    if (tid < TB) {
        int r = row0 + tid;
        tok_s[tid] = (r < n_e) ? bidx[e * N_TOK + r] : -1;
        p_s[tid]   = (r < n_e) ? bp[e * N_TOK + r] : 0.f;
    }
    BARRIER();

    // ---- stage xb (bf16) -> xs frag-major: pure copies, no VALU.
    {
        const int tok = tid >> 3;
        const int tk  = tok_s[tok];
        const short* xrow = xb + (size_t)(tk < 0 ? 0 : tk) * D;
#pragma unroll
        for (int i = 0; i < 2; ++i) {
            const int dblk = (tid & 7) * 2 + i;
            uint4 v0 = make_uint4(0, 0, 0, 0), v1 = make_uint4(0, 0, 0, 0);
            if (tk >= 0) {
                v0 = *(const uint4*)(xrow + dblk * 16);
                v1 = *(const uint4*)(xrow + dblk * 16 + 8);
            }
            short* dp = &xs[dblk * 1024 + tok * 16];
            *(uint4*)(dp)     = v0;
            *(uint4*)(dp + 8) = v1;
        }
    }

    f32x16 acc[2];   // [tp tok-half], cols wid*32 + l31
#pragma unroll
    for (int a = 0; a < 2; ++a)
#pragma unroll
        for (int r = 0; r < 16; ++r) acc[a][r] = 0.f;

    const short* w1e = w1f + (size_t)e * (32 * 16 * 512);
    const short* w2e = w2f + (size_t)e * (8 * 64 * 512);
    const float* b1e = b1 + e * DFF;

    BARRIER();   // xs ready

    for (int fc = 0; fc < 4; ++fc) {
        // ---------- GEMM1: wave wid -> f-strip [fc*256+wid*32, +32) x 64 tok
        f32x16 h0, h1;
#pragma unroll
        for (int r = 0; r < 16; ++r) { h0[r] = 0.f; h1[r] = 0.f; }

        const short* w1p = w1e + ((size_t)(fc * 8 + wid) * 16) * 512 + lane * 8;
        __builtin_amdgcn_s_setprio(1);
        {
            bf16x8 a0 = *(const bf16x8*)(w1p);
            bf16x8 x0 = *(const bf16x8*)&xs[l31 * 16 + g * 8];
            bf16x8 x1 = *(const bf16x8*)&xs[512 + l31 * 16 + g * 8];
#pragma unroll
            for (int db = 0; db < 16; ++db) {
                bf16x8 an, y0, y1;
                if (db < 15) {
                    an = *(const bf16x8*)(w1p + (db + 1) * 512);
                    y0 = *(const bf16x8*)&xs[(db + 1) * 1024 + l31 * 16 + g * 8];
                    y1 = *(const bf16x8*)&xs[(db + 1) * 1024 + 512 + l31 * 16 + g * 8];
                }
                h0 = __builtin_amdgcn_mfma_f32_32x32x16_bf16(a0, x0, h0, 0, 0, 0);
                h1 = __builtin_amdgcn_mfma_f32_32x32x16_bf16(a0, x1, h1, 0, 0, 0);
                if (db < 15) { a0 = an; x0 = y0; x1 = y1; }
            }
        }
        __builtin_amdgcn_s_setprio(0);

        BARRIER();   // prev GEMM2 hs reads done

        // ---------- pack: bias+relu + cvt_pk -> hs frag-major
#pragma unroll
        for (int tp = 0; tp < 2; ++tp) {
            const f32x16& hh = tp ? h1 : h0;
#pragma unroll
            for (int m = 0; m < 4; ++m) {
                float4 bq = *(const float4*)(b1e + fc * 256 + wid * 32 + 8 * m + 4 * g);
                float v0 = fmaxf(hh[4 * m + 0] + bq.x, 0.f);
                float v1 = fmaxf(hh[4 * m + 1] + bq.y, 0.f);
                float v2 = fmaxf(hh[4 * m + 2] + bq.z, 0.f);
                float v3 = fmaxf(hh[4 * m + 3] + bq.w, 0.f);
                uint2 pk;
                pk.x = cvtpk(v0, v1);
                pk.y = cvtpk(v2, v3);
                const int fragid = (2 * wid + (m >> 1)) * 2 + tp;
                *(uint2*)&hs[fragid * 512 + ((m & 1) * 32 + l31) * 8 + 4 * g] = pk;
            }
        }

        // ---------- prefetch first w2 frag above the barrier
        const short* w2p = w2e + ((size_t)wid * 64 + fc * 16) * 512 + lane * 8;
        bf16x8 wcur = *(const bf16x8*)(w2p);

        BARRIER();   // hs ready; in-flight vmem NOT drained

        // ---------- GEMM2: wave wid -> cols [wid*32, +32), k over 256 f
        __builtin_amdgcn_s_setprio(1);
        {
            bf16x8 ha0 = *(const bf16x8*)&hs[0 * 512 + lane * 8];
            bf16x8 ha1 = *(const bf16x8*)&hs[1 * 512 + lane * 8];
#pragma unroll
            for (int kt = 0; kt < 16; ++kt) {
                bf16x8 wn, hb0, hb1;
                if (kt < 15) {
                    wn  = *(const bf16x8*)(w2p + (kt + 1) * 512);
                    hb0 = *(const bf16x8*)&hs[((kt + 1) * 2 + 0) * 512 + lane * 8];
                    hb1 = *(const bf16x8*)&hs[((kt + 1) * 2 + 1) * 512 + lane * 8];
                }
                acc[0] = __builtin_amdgcn_mfma_f32_32x32x16_bf16(ha0, wcur, acc[0], 0, 0, 0);
                acc[1] = __builtin_amdgcn_mfma_f32_32x32x16_bf16(ha1, wcur, acc[1], 0, 0, 0);
                if (kt < 15) { wcur = wn; ha0 = hb0; ha1 = hb1; }
            }
        }
        __builtin_amdgcn_s_setprio(0);
    }

    // ---- epilogue ----
    const float* b2e = b2 + e * D;
    const int col = wid * 32 + l31;
    const float bv = b2e[col];
    if (staged) {
        // compact bf16 rows: [cbase + row0, cbase + row0 + TB)
        unsigned short* ype = yp + ((size_t)(cbase + row0)) * 256;
#pragma unroll
        for (int tp = 0; tp < 2; ++tp) {
#pragma unroll
            for (int r = 0; r < 16; ++r) {
                const int tl = tp * 32 + (r & 3) + 8 * (r >> 2) + 4 * g;
                if (tok_s[tl] >= 0)
                    __builtin_nontemporal_store(
                        f2bf((acc[tp][r] + bv) * p_s[tl]),
                        &ype[(size_t)tl * 256 + col]);
            }
        }
    } else {
#pragma unroll
        for (int tp = 0; tp < 2; ++tp) {
#pragma unroll
            for (int r = 0; r < 16; ++r) {
                const int tl = tp * 32 + (r & 3) + 8 * (r >> 2) + 4 * g;
                const int tk = tok_s[tl];
                if (tk >= 0)
                    atomicAdd(out + (size_t)tk * D + col,
                              (acc[tp][r] + bv) * p_s[tl]);
            }
        }
    }
}

// ===========================================================================
// Combine: out[t] = bf2f(yp[compact(o1)]) + bf2f(yp[compact(o2)]),
// compact(o) = prefix(cnt)[o>>15] + (o & 32767). One wave per token row.
// ===========================================================================
__global__ __launch_bounds__(256) void combine(
    const unsigned short* __restrict__ yp, const int2* __restrict__ opos,
    const int* __restrict__ cnt, float* __restrict__ out) {
    __shared__ int cb[NE];
    if (threadIdx.x == 0) {
        int s = 0;
#pragma unroll
        for (int j = 0; j < NE; ++j) { cb[j] = s; s += cnt[j]; }
    }
    __syncthreads();
    const int gid   = blockIdx.x * 256 + threadIdx.x;  // float4 index
    const int t     = gid >> 6;
    const int lane4 = gid & 63;
    const int2 o = opos[t];
    const size_t r1 = (size_t)(cb[o.x >> 15] + (o.x & (N_TOK - 1)));
    const size_t r2 = (size_t)(cb[o.y >> 15] + (o.y & (N_TOK - 1)));
    const ushort4 a = *(const ushort4*)(yp + r1 * 256 + lane4 * 4);
    const ushort4 b = *(const ushort4*)(yp + r2 * 256 + lane4 * 4);
    float4 r;
    r.x = bf2f(a.x) + bf2f(b.x);
    r.y = bf2f(a.y) + bf2f(b.y);
    r.z = bf2f(a.z) + bf2f(b.z);
    r.w = bf2f(a.w) + bf2f(b.w);
    ((float4*)out)[gid] = r;
}

// ---------------------------------------------------------------------------
extern "C" void kernel_launch(void* const* d_in, const int* in_sizes, int n_in,
                              void* d_out, int out_size, void* d_ws, size_t ws_size,
                              hipStream_t stream) {
    const float* x  = (const float*)d_in[0];
    const float* gw = (const float*)d_in[1];
    const float* gb = (const float*)d_in[2];
    const float* w1 = (const float*)d_in[3];
    const float* b1 = (const float*)d_in[4];
    const float* w2 = (const float*)d_in[5];
    const float* b2 = (const float*)d_in[6];
    float* out = (float*)d_out;

    // ws (compact): cnt 256B | bidx 1MB | bp 1MB | opos 512KB
    //   | w1f 4MB | w2f 4MB | xb 16MB | yp (bf16) 32MB  => 58.5MB total.
    char* ws = (char*)d_ws;
    size_t off = 0;
    int*   cnt   = (int*)(ws + off);  off += 256;
    int*   bidx  = (int*)(ws + off);  off += (size_t)NE * N_TOK * 4;
    float* bp    = (float*)(ws + off); off += (size_t)NE * N_TOK * 4;
    int2*  opos  = (int2*)(ws + off); off += (size_t)N_TOK * 8;
    short* w1f   = (short*)(ws + off); off += (size_t)NE * D * DFF * 2;
    short* w2f   = (short*)(ws + off); off += (size_t)NE * D * DFF * 2;
    short* xb    = (short*)(ws + off); off += (size_t)N_TOK * D * 2;
    unsigned short* yp = (unsigned short*)(ws + off);
    off += (size_t)2 * N_TOK * D * 2;
    const int staged = (ws_size >= off) ? 1 : 0;

    hipMemsetAsync(cnt, 0, 256, stream);
    if (!staged)
        hipMemsetAsync(d_out, 0, (size_t)out_size * sizeof(float), stream);

    // fused: gate+x-conv (128, FIRST) + w1 prep (1024) + w2 prep (1024)
    prep_gate<<<128 + 2048, 256, 0, stream>>>(
        w1, w2, w1f, w2f, x, xb, gw, gb, cnt, bidx, bp, opos);
    expert_ffn<<<NE * (N_TOK / TB), 512, 0, stream>>>(xb, w1f, w2f, b1, b2,
                                                      cnt, bidx, bp, out, yp, staged);
    if (staged)
        combine<<<(N_TOK * D / 4) / 256, 256, 0, stream>>>(yp, opos, cnt, out);
}

// Round 18
// 140.729 us; speedup vs baseline: 1.1734x; 1.0080x over previous
//
#include <hip/hip_runtime.h>

#define N_TOK 32768
#define D 256
#define DFF 1024
#define NE 8
#define TB 64    // tokens per expert_ffn block

typedef __attribute__((ext_vector_type(16))) float f32x16;
typedef __attribute__((ext_vector_type(8)))  short bf16x8;

// Raw barrier: LDS writes made visible (lgkmcnt(0)) but NO vmcnt drain --
// in-flight global weight loads survive the barrier (T3/T4; verified r8).
#define BARRIER() do {                                        \
    asm volatile("s_waitcnt lgkmcnt(0)" ::: "memory");        \
    __builtin_amdgcn_s_barrier();                             \
    __builtin_amdgcn_sched_barrier(0);                        \
} while (0)

// packed fp32x2 -> bf16x2 (RNE, single VALU inst)
__device__ __forceinline__ unsigned cvtpk(float lo, float hi) {
    unsigned r;
    asm("v_cvt_pk_bf16_f32 %0, %1, %2" : "=v"(r) : "v"(lo), "v"(hi));
    return r;
}

// scalar fp32 -> bf16 (RNE) for the scattered epilogue stores
__device__ __forceinline__ unsigned short f2bf(float f) {
    union { float f; unsigned u; } v; v.f = f;
    unsigned r = v.u + 0x7FFFu + ((v.u >> 16) & 1u);
    return (unsigned short)(r >> 16);
}

__device__ __forceinline__ float bf2f(unsigned short u) {
    union { unsigned u; float f; } v; v.u = (unsigned)u << 16;
    return v.f;
}

// ===========================================================================
// Fused gate + prep (1 launch). Blocks [0,128): GATE (fp64 logits, top-2,
// softmax, binning) with x->bf16 conversion fused. [128,1152): w1 prep;
// [1152,2176): w2 prep. Layout conventions verified rounds 2-17.
//  w1f: frag=(e*32+fblk)*16+dblk; elem f=fblk*32+(l&31), d=dblk*16+(l>>5)*8+j
//  w2f: frag=(e*8+cblk)*64+fblk; elem col=cblk*32+(l&31), f=fblk*16+(l>>5)*8+j
// ===========================================================================
__global__ __launch_bounds__(256) void prep_gate(
    const float* __restrict__ w1, const float* __restrict__ w2,
    short* __restrict__ w1f, short* __restrict__ w2f,
    const float* __restrict__ x, short* __restrict__ xb,
    const float* __restrict__ gw, const float* __restrict__ gb,
    int* __restrict__ cnt, int* __restrict__ bidx, float* __restrict__ bp,
    int2* __restrict__ opos) {
    const int b = blockIdx.x;
    if (b >= 128) {
        if (b < 1152) {
            const int gid  = (b - 128) * 256 + threadIdx.x;
            const int lane = gid & 63;
            const int frag = gid >> 6;
            const int dblk = frag & 15;
            const int fblk = (frag >> 4) & 31;
            const int e    = frag >> 9;
            const int l31 = lane & 31, g = lane >> 5;

            const float* src = w1 + ((size_t)e * 256 + dblk * 16 + g * 8) * 1024
                                  + fblk * 32 + l31;
            unsigned u[4];
#pragma unroll
            for (int jp = 0; jp < 4; ++jp)
                u[jp] = cvtpk(src[(size_t)(jp * 2) * 1024],
                              src[(size_t)(jp * 2 + 1) * 1024]);
            *(uint4*)(w1f + (size_t)gid * 8) = make_uint4(u[0], u[1], u[2], u[3]);
        } else {
            const int gid  = (b - 1152) * 256 + threadIdx.x;
            const int lane = gid & 63;
            const int frag = gid >> 6;
            const int fblk = frag & 63;
            const int cblk = (frag >> 6) & 7;
            const int e    = frag >> 9;
            const int l31 = lane & 31, g = lane >> 5;

            const float* src = w2 + ((size_t)e * 1024 + fblk * 16 + g * 8) * 256
                                  + cblk * 32 + l31;
            unsigned u[4];
#pragma unroll
            for (int jp = 0; jp < 4; ++jp)
                u[jp] = cvtpk(src[(size_t)(jp * 2) * 256],
                              src[(size_t)(jp * 2 + 1) * 256]);
            *(uint4*)(w2f + (size_t)gid * 8) = make_uint4(u[0], u[1], u[2], u[3]);
        }
        return;
    }

    // ---------------- gate (+ fused x->bf16) ----------------
    __shared__ float gws[2048];   // [d][e]
    __shared__ int   se1[256], se2[256];
    __shared__ float sp1[256], sp2[256];
    __shared__ int   hist[NE], base_[NE];

    const int tid = threadIdx.x;
#pragma unroll
    for (int i = 0; i < 8; ++i) gws[tid + 256 * i] = gw[tid + 256 * i];
    if (tid < NE) hist[tid] = 0;
    __syncthreads();

    const int t = b * 256 + tid;
    const float* xr = x + (size_t)t * D;
    short* xbr = xb + (size_t)t * D;

    double acc[NE];
#pragma unroll
    for (int e = 0; e < NE; ++e) acc[e] = 0.0;

    for (int d0 = 0; d0 < 256; d0 += 8) {
        float4 xv0 = *(const float4*)(xr + d0);
        float4 xv1 = *(const float4*)(xr + d0 + 4);
        float xa[8] = {xv0.x, xv0.y, xv0.z, xv0.w, xv1.x, xv1.y, xv1.z, xv1.w};
#pragma unroll
        for (int j = 0; j < 8; ++j) {
            float4 ga  = *(const float4*)&gws[(d0 + j) * 8];
            float4 gbb = *(const float4*)&gws[(d0 + j) * 8 + 4];
            double xd = (double)xa[j];
            acc[0] += xd * (double)ga.x;  acc[1] += xd * (double)ga.y;
            acc[2] += xd * (double)ga.z;  acc[3] += xd * (double)ga.w;
            acc[4] += xd * (double)gbb.x; acc[5] += xd * (double)gbb.y;
            acc[6] += xd * (double)gbb.z; acc[7] += xd * (double)gbb.w;
        }
        uint4 o;
        o.x = cvtpk(xv0.x, xv0.y);  o.y = cvtpk(xv0.z, xv0.w);
        o.z = cvtpk(xv1.x, xv1.y);  o.w = cvtpk(xv1.z, xv1.w);
        *(uint4*)(xbr + d0) = o;
    }

    double l[NE];
#pragma unroll
    for (int e = 0; e < NE; ++e) l[e] = acc[e] + (double)gb[e];
    int e1 = 0;
#pragma unroll
    for (int e = 1; e < NE; ++e) if (l[e] > l[e1]) e1 = e;
    int e2 = (e1 == 0) ? 1 : 0;
#pragma unroll
    for (int e = 0; e < NE; ++e) if (e != e1 && l[e] > l[e2]) e2 = e;

    double s = 0.0;
#pragma unroll
    for (int e = 0; e < NE; ++e) s += exp(l[e] - l[e1]);
    se1[tid] = e1; se2[tid] = e2;
    sp1[tid] = (float)(1.0 / s);
    sp2[tid] = (float)(exp(l[e2] - l[e1]) / s);
    __syncthreads();

    const int pos1 = atomicAdd(&hist[se1[tid]], 1);
    const int pos2 = atomicAdd(&hist[se2[tid]], 1);
    __syncthreads();
    if (tid < NE) base_[tid] = atomicAdd(&cnt[tid], hist[tid]);
    __syncthreads();

    const int o1 = se1[tid] * N_TOK + base_[se1[tid]] + pos1;
    const int o2 = se2[tid] * N_TOK + base_[se2[tid]] + pos2;
    bidx[o1] = t;  bp[o1] = sp1[tid];
    bidx[o2] = t;  bp[o2] = sp2[tid];
    opos[t] = make_int2(o1, o2);
}

// ===========================================================================
// Expert FFN v18 = v17 (measured optimum: ~98us, MfmaUtil 30%) with pad-row
// zero-fill dropped from staging (pad rows read row-0 data; all consuming
// stores are behind the tok_s>=0 guard, so results untouched). Structural
// plateau: arch 56 + acc 64 = 120 regs sits exactly at the 128-reg /
// 4-waves-per-SIMD cliff — any deeper pipelining (+12 regs) halves
// occupancy; hs dbuf (+32KB) halves resident blocks. Phases additive:
// MFMA 29 + LDS 29 + L2 29 + VALU 15 ~= 98us wall.
// ===========================================================================
__global__ __launch_bounds__(512, 4) void expert_ffn(
    const short* __restrict__ xb,
    const short* __restrict__ w1f,
    const short* __restrict__ w2f,
    const float* __restrict__ b1, const float* __restrict__ b2,
    const int* __restrict__ cnt, const int* __restrict__ bidx,
    const float* __restrict__ bp, float* __restrict__ out,
    unsigned short* __restrict__ yp, int staged) {
    const int e    = blockIdx.x & 7;
    const int tile = blockIdx.x >> 3;
    const int n_e  = cnt[e];
    const int row0 = tile * TB;
    if (row0 >= n_e) return;

    __shared__ short xs[16 * 64 * 16];   // 32KB [dblk][tok64][16] frag-major
    __shared__ short hs[32 * 512];       // 32KB [frag(kt*2+tp)][512]
    __shared__ int   tok_s[TB];
    __shared__ float p_s[TB];

    const int tid  = threadIdx.x;
    const int lane = tid & 63, wid = tid >> 6;   // wid 0..7
    const int l31  = lane & 31, g = lane >> 5;

    // compact yp base for this expert: sum of cnt[j], j<e (deterministic)
    int cbase = 0;
    for (int j = 0; j < e; ++j) cbase += cnt[j];

    if (tid < TB) {
        int r = row0 + tid;
        tok_s[tid] = (r < n_e) ? bidx[e * N_TOK + r] : -1;
        p_s[tid]   = (r < n_e) ? bp[e * N_TOK + r] : 0.f;
    }
    BARRIER();

    // ---- stage xb (bf16) -> xs frag-major: pure copies. Pad rows load
    // row 0 (finite data); their outputs are discarded by the epilogue guard.
    {
        const int tok = tid >> 3;
        const int tk  = tok_s[tok];
        const short* xrow = xb + (size_t)(tk < 0 ? 0 : tk) * D;
#pragma unroll
        for (int i = 0; i < 2; ++i) {
            const int dblk = (tid & 7) * 2 + i;
            uint4 v0 = *(const uint4*)(xrow + dblk * 16);
            uint4 v1 = *(const uint4*)(xrow + dblk * 16 + 8);
            short* dp = &xs[dblk * 1024 + tok * 16];
            *(uint4*)(dp)     = v0;
            *(uint4*)(dp + 8) = v1;
        }
    }

    f32x16 acc[2];   // [tp tok-half], cols wid*32 + l31
#pragma unroll
    for (int a = 0; a < 2; ++a)
#pragma unroll
        for (int r = 0; r < 16; ++r) acc[a][r] = 0.f;

    const short* w1e = w1f + (size_t)e * (32 * 16 * 512);
    const short* w2e = w2f + (size_t)e * (8 * 64 * 512);
    const float* b1e = b1 + e * DFF;

    BARRIER();   // xs ready

    for (int fc = 0; fc < 4; ++fc) {
        // ---------- GEMM1: wave wid -> f-strip [fc*256+wid*32, +32) x 64 tok
        f32x16 h0, h1;
#pragma unroll
        for (int r = 0; r < 16; ++r) { h0[r] = 0.f; h1[r] = 0.f; }

        const short* w1p = w1e + ((size_t)(fc * 8 + wid) * 16) * 512 + lane * 8;
        __builtin_amdgcn_s_setprio(1);
        {
            bf16x8 a0 = *(const bf16x8*)(w1p);
            bf16x8 x0 = *(const bf16x8*)&xs[l31 * 16 + g * 8];
            bf16x8 x1 = *(const bf16x8*)&xs[512 + l31 * 16 + g * 8];
#pragma unroll
            for (int db = 0; db < 16; ++db) {
                bf16x8 an, y0, y1;
                if (db < 15) {
                    an = *(const bf16x8*)(w1p + (db + 1) * 512);
                    y0 = *(const bf16x8*)&xs[(db + 1) * 1024 + l31 * 16 + g * 8];
                    y1 = *(const bf16x8*)&xs[(db + 1) * 1024 + 512 + l31 * 16 + g * 8];
                }
                h0 = __builtin_amdgcn_mfma_f32_32x32x16_bf16(a0, x0, h0, 0, 0, 0);
                h1 = __builtin_amdgcn_mfma_f32_32x32x16_bf16(a0, x1, h1, 0, 0, 0);
                if (db < 15) { a0 = an; x0 = y0; x1 = y1; }
            }
        }
        __builtin_amdgcn_s_setprio(0);

        BARRIER();   // prev GEMM2 hs reads done

        // ---------- pack: bias+relu + cvt_pk -> hs frag-major
#pragma unroll
        for (int tp = 0; tp < 2; ++tp) {
            const f32x16& hh = tp ? h1 : h0;
#pragma unroll
            for (int m = 0; m < 4; ++m) {
                float4 bq = *(const float4*)(b1e + fc * 256 + wid * 32 + 8 * m + 4 * g);
                float v0 = fmaxf(hh[4 * m + 0] + bq.x, 0.f);
                float v1 = fmaxf(hh[4 * m + 1] + bq.y, 0.f);
                float v2 = fmaxf(hh[4 * m + 2] + bq.z, 0.f);
                float v3 = fmaxf(hh[4 * m + 3] + bq.w, 0.f);
                uint2 pk;
                pk.x = cvtpk(v0, v1);
                pk.y = cvtpk(v2, v3);
                const int fragid = (2 * wid + (m >> 1)) * 2 + tp;
                *(uint2*)&hs[fragid * 512 + ((m & 1) * 32 + l31) * 8 + 4 * g] = pk;
            }
        }

        // ---------- prefetch first w2 frag above the barrier
        const short* w2p = w2e + ((size_t)wid * 64 + fc * 16) * 512 + lane * 8;
        bf16x8 wcur = *(const bf16x8*)(w2p);

        BARRIER();   // hs ready; in-flight vmem NOT drained

        // ---------- GEMM2: wave wid -> cols [wid*32, +32), k over 256 f
        __builtin_amdgcn_s_setprio(1);
        {
            bf16x8 ha0 = *(const bf16x8*)&hs[0 * 512 + lane * 8];
            bf16x8 ha1 = *(const bf16x8*)&hs[1 * 512 + lane * 8];
#pragma unroll
            for (int kt = 0; kt < 16; ++kt) {
                bf16x8 wn, hb0, hb1;
                if (kt < 15) {
                    wn  = *(const bf16x8*)(w2p + (kt + 1) * 512);
                    hb0 = *(const bf16x8*)&hs[((kt + 1) * 2 + 0) * 512 + lane * 8];
                    hb1 = *(const bf16x8*)&hs[((kt + 1) * 2 + 1) * 512 + lane * 8];
                }
                acc[0] = __builtin_amdgcn_mfma_f32_32x32x16_bf16(ha0, wcur, acc[0], 0, 0, 0);
                acc[1] = __builtin_amdgcn_mfma_f32_32x32x16_bf16(ha1, wcur, acc[1], 0, 0, 0);
                if (kt < 15) { wcur = wn; ha0 = hb0; ha1 = hb1; }
            }
        }
        __builtin_amdgcn_s_setprio(0);
    }

    // ---- epilogue ----
    const float* b2e = b2 + e * D;
    const int col = wid * 32 + l31;
    const float bv = b2e[col];
    if (staged) {
        // compact bf16 rows: [cbase + row0, cbase + row0 + TB)
        unsigned short* ype = yp + ((size_t)(cbase + row0)) * 256;
#pragma unroll
        for (int tp = 0; tp < 2; ++tp) {
#pragma unroll
            for (int r = 0; r < 16; ++r) {
                const int tl = tp * 32 + (r & 3) + 8 * (r >> 2) + 4 * g;
                if (tok_s[tl] >= 0)
                    __builtin_nontemporal_store(
                        f2bf((acc[tp][r] + bv) * p_s[tl]),
                        &ype[(size_t)tl * 256 + col]);
            }
        }
    } else {
#pragma unroll
        for (int tp = 0; tp < 2; ++tp) {
#pragma unroll
            for (int r = 0; r < 16; ++r) {
                const int tl = tp * 32 + (r & 3) + 8 * (r >> 2) + 4 * g;
                const int tk = tok_s[tl];
                if (tk >= 0)
                    atomicAdd(out + (size_t)tk * D + col,
                              (acc[tp][r] + bv) * p_s[tl]);
            }
        }
    }
}

// ===========================================================================
// Combine: out[t] = bf2f(yp[compact(o1)]) + bf2f(yp[compact(o2)]),
// compact(o) = prefix(cnt)[o>>15] + (o & 32767). One wave per token row.
// ===========================================================================
__global__ __launch_bounds__(256) void combine(
    const unsigned short* __restrict__ yp, const int2* __restrict__ opos,
    const int* __restrict__ cnt, float* __restrict__ out) {
    __shared__ int cb[NE];
    if (threadIdx.x == 0) {
        int s = 0;
#pragma unroll
        for (int j = 0; j < NE; ++j) { cb[j] = s; s += cnt[j]; }
    }
    __syncthreads();
    const int gid   = blockIdx.x * 256 + threadIdx.x;  // float4 index
    const int t     = gid >> 6;
    const int lane4 = gid & 63;
    const int2 o = opos[t];
    const size_t r1 = (size_t)(cb[o.x >> 15] + (o.x & (N_TOK - 1)));
    const size_t r2 = (size_t)(cb[o.y >> 15] + (o.y & (N_TOK - 1)));
    const ushort4 a = *(const ushort4*)(yp + r1 * 256 + lane4 * 4);
    const ushort4 b = *(const ushort4*)(yp + r2 * 256 + lane4 * 4);
    float4 r;
    r.x = bf2f(a.x) + bf2f(b.x);
    r.y = bf2f(a.y) + bf2f(b.y);
    r.z = bf2f(a.z) + bf2f(b.z);
    r.w = bf2f(a.w) + bf2f(b.w);
    ((float4*)out)[gid] = r;
}

// ---------------------------------------------------------------------------
extern "C" void kernel_launch(void* const* d_in, const int* in_sizes, int n_in,
                              void* d_out, int out_size, void* d_ws, size_t ws_size,
                              hipStream_t stream) {
    const float* x  = (const float*)d_in[0];
    const float* gw = (const float*)d_in[1];
    const float* gb = (const float*)d_in[2];
    const float* w1 = (const float*)d_in[3];
    const float* b1 = (const float*)d_in[4];
    const float* w2 = (const float*)d_in[5];
    const float* b2 = (const float*)d_in[6];
    float* out = (float*)d_out;

    // ws (compact): cnt 256B | bidx 1MB | bp 1MB | opos 512KB
    //   | w1f 4MB | w2f 4MB | xb 16MB | yp (bf16) 32MB  => 58.5MB total.
    char* ws = (char*)d_ws;
    size_t off = 0;
    int*   cnt   = (int*)(ws + off);  off += 256;
    int*   bidx  = (int*)(ws + off);  off += (size_t)NE * N_TOK * 4;
    float* bp    = (float*)(ws + off); off += (size_t)NE * N_TOK * 4;
    int2*  opos  = (int2*)(ws + off); off += (size_t)N_TOK * 8;
    short* w1f   = (short*)(ws + off); off += (size_t)NE * D * DFF * 2;
    short* w2f   = (short*)(ws + off); off += (size_t)NE * D * DFF * 2;
    short* xb    = (short*)(ws + off); off += (size_t)N_TOK * D * 2;
    unsigned short* yp = (unsigned short*)(ws + off);
    off += (size_t)2 * N_TOK * D * 2;
    const int staged = (ws_size >= off) ? 1 : 0;

    hipMemsetAsync(cnt, 0, 256, stream);
    if (!staged)
        hipMemsetAsync(d_out, 0, (size_t)out_size * sizeof(float), stream);

    // fused: gate+x-conv (128, FIRST) + w1 prep (1024) + w2 prep (1024)
    prep_gate<<<128 + 2048, 256, 0, stream>>>(
        w1, w2, w1f, w2f, x, xb, gw, gb, cnt, bidx, bp, opos);
    expert_ffn<<<NE * (N_TOK / TB), 512, 0, stream>>>(xb, w1f, w2f, b1, b2,
                                                      cnt, bidx, bp, out, yp, staged);
    if (staged)
        combine<<<(N_TOK * D / 4) / 256, 256, 0, stream>>>(yp, opos, cnt, out);
}